// Round 6
// baseline (446.341 us; speedup 1.0000x reference)
//
#include <hip/hip_runtime.h>
#include <stdint.h>

typedef __bf16 bf16;
typedef bf16 bf16x8 __attribute__((ext_vector_type(8)));
typedef float f32x4 __attribute__((ext_vector_type(4)));

#define N_NODES 131072
#define D_IN    128
#define KEXP    1024
#define H_DIM   512
#define NGRP    4
#define NPG     32768   // N_NODES / NGRP
#define F_SEG   8192
#define G_SEG   32
#define C_OUT   16

// async global->LDS DMA, 16B per lane; LDS dest = wave-uniform base + lane*16
typedef const __attribute__((address_space(1))) void* gas_t;
typedef __attribute__((address_space(3))) void* las_t;
__device__ __forceinline__ void cp16_async(const bf16* g, bf16* l) {
    __builtin_amdgcn_global_load_lds((gas_t)g, (las_t)l, 16, 0, 0);
}

// order-preserving fp32 <-> uint32 encode for atomicMax-based segment max
__device__ __forceinline__ uint32_t enc_f32(float f) {
    uint32_t b = __float_as_uint(f);
    return (b & 0x80000000u) ? ~b : (b | 0x80000000u);
}
__device__ __forceinline__ float dec_f32(uint32_t k) {
    uint32_t b = (k & 0x80000000u) ? (k & 0x7FFFFFFFu) : ~k;
    return __uint_as_float(b);
}

// ---------------------------------------------------------------------------
// One-time weight cast + swizzle into MFMA-fragment order, plus EMB zero-init
// (EMB accumulates uint-encoded fp32 maxima via atomicMax; ws is poisoned
// 0xAA each launch so it must be zeroed -- key 0 == -inf).
//
// W1F[g][kc(32)][f=ks*2+nt (8)][lane(64)][j(8)]
//     = W1[g][d = ks*32 + quad*8 + j][k' = kc*32 + nt*16 + ln]
// W2F[g][n0t2(2)][kc(32)][f(16)][lane][j]
//     = W2[g][k = kc*32 + quad*8 + j][n = n0t2*256 + f*16 + ln]
// ---------------------------------------------------------------------------
__global__ void convert_weights(const float* __restrict__ W1,
                                const float* __restrict__ W2,
                                bf16* __restrict__ W1F,
                                bf16* __restrict__ W2F,
                                uint32_t* __restrict__ EMBu)
{
    int t = blockIdx.x * 256 + threadIdx.x;
    if (t < 65536) {
        int slot = t & 63, f = (t >> 6) & 7, kc = (t >> 9) & 31, g = t >> 14;
        int ks = f >> 1, nt = f & 1, quad = slot >> 4, ln = slot & 15;
        int k = kc * 32 + nt * 16 + ln;
        const float* src = W1 + ((size_t)(g * 128 + ks * 32 + quad * 8)) * 1024 + k;
        bf16x8 v;
        #pragma unroll
        for (int j = 0; j < 8; ++j) v[j] = (bf16)src[(size_t)j * 1024];
        *(bf16x8*)(W1F + (size_t)t * 8) = v;
    } else if (t < 327680) {
        int u = t - 65536;
        int slot = u & 63, f = (u >> 6) & 15, kc = (u >> 10) & 31;
        int n0t2 = (u >> 15) & 1, g = u >> 16;
        int quad = slot >> 4, ln = slot & 15;
        int k = kc * 32 + quad * 8;
        int n = n0t2 * 256 + f * 16 + ln;
        const float* src = W2 + ((size_t)(g * 1024 + k)) * 512 + n;
        bf16x8 v;
        #pragma unroll
        for (int j = 0; j < 8; ++j) v[j] = (bf16)src[(size_t)j * 512];
        *(bf16x8*)(W2F + (size_t)u * 8) = v;
    } else {
        int z = t - 327680;
        if (z < F_SEG * H_DIM) EMBu[z] = 0u;   // encoded -inf
    }
}

// ---------------------------------------------------------------------------
// Fused gather + GEMM1(relu) + GEMM2 + segment-max scatter. 256 threads.
// Round-6: stage 2 wave-splits N (each wave: 128 rows x 64 cols) -> W2 LDS
// reads per block-kc drop 64->16 KB (whole-kernel LDS pipe was the binding
// resource at R5). Two barriers per kc; DMA prefetch issued AFTER barrier B
// so B drains nothing and A drains a DMA with a full stage-2 flight time.
// Epilogue: fp32 order-encoded atomicMax directly into EMB (NF + pool
// kernel eliminated: -134 MB HBM write, -134 MB read, -1 dispatch).
// LDS: sW1 2x8K + sW2 2x16K + sH 8K = 56 KB -> 2 blocks/CU.
// ---------------------------------------------------------------------------
__global__ __launch_bounds__(256, 2)
void mlp_kernel(const float* __restrict__ x,
                const int*   __restrict__ gidx,
                const bf16*  __restrict__ W1F,
                const float* __restrict__ b1,
                const bf16*  __restrict__ W2F,
                const float* __restrict__ b2,
                uint32_t*    __restrict__ EMBu)
{
    __shared__ __align__(16) bf16 sW1[2][4096]; // [f=ks*2+nt (8)][lane][8]
    __shared__ __align__(16) bf16 sW2[2][8192]; // [f (16)][lane][8]
    __shared__ __align__(16) bf16 sH[4096];     // [frag m (8)][lane][8]

    const int tid  = threadIdx.x;
    const int bid  = blockIdx.x;
    const int g    = bid >> 9;
    const int rem  = bid & 511;
    const int m0   = (rem >> 1) * 128;
    const int n0t2 = rem & 1;

    const int wave = tid >> 6;
    const int lane = tid & 63;
    const int quad = lane >> 4;
    const int ln   = lane & 15;

    const int*  gI  = gidx + g * NPG + m0;
    const bf16* W1g = W1F + (size_t)g * 131072;                   // [kc][4096]
    const bf16* W2g = W2F + (size_t)(g * 2 + n0t2) * 262144;      // [kc][8192]
    const float* b1g = b1 + g * KEXP;
    const float* b2g = b2 + g * H_DIM + n0t2 * 256;

    // ---- gather x A-frags straight into registers (reused all 32 kc) ----
    bf16x8 xf[8];
    #pragma unroll
    for (int i = 0; i < 8; ++i) {
        int row  = wave * 32 + (i >> 2) * 16 + ln;
        int node = gI[row];
        const float* src = x + (size_t)node * D_IN + (i & 3) * 32 + quad * 8;
        float4 a = *(const float4*)src;
        float4 b = *(const float4*)(src + 4);
        bf16x8 v;
        v[0] = (bf16)a.x; v[1] = (bf16)a.y; v[2] = (bf16)a.z; v[3] = (bf16)a.w;
        v[4] = (bf16)b.x; v[5] = (bf16)b.y; v[6] = (bf16)b.z; v[7] = (bf16)b.w;
        xf[i] = v;
    }

    f32x4 acc2[8][4];   // [mt: rows mt*16..+16][nt: cols wave*64+nt*16..+16]
    #pragma unroll
    for (int a = 0; a < 8; ++a)
        #pragma unroll
        for (int b = 0; b < 4; ++b)
            acc2[a][b] = (f32x4){0.f, 0.f, 0.f, 0.f};

    // ---- preloop: DMA chunk 0 into buf 0 ----
    #pragma unroll
    for (int r = 0; r < 2; ++r) {
        int c = r * 4 + wave;
        cp16_async(W1g + c * 512 + lane * 8, sW1[0] + c * 512);
    }
    #pragma unroll
    for (int r = 0; r < 4; ++r) {
        int c = r * 4 + wave;
        cp16_async(W2g + c * 512 + lane * 8, sW2[0] + c * 512);
    }

    #pragma unroll 1
    for (int kc = 0; kc < 32; ++kc) {
        __syncthreads();   // A: drains DMA(kc) (flew during stage2(kc-1));
                           //    separates stage2(kc-1) sH reads from new writes

        // ---- stage 1: h[this wave's 32 rows][k' 32] = relu(x @ W1c + b1) ----
        const bf16* w1buf = sW1[kc & 1];
        float bias_v[2];
        #pragma unroll
        for (int nt = 0; nt < 2; ++nt)
            bias_v[nt] = b1g[kc * 32 + nt * 16 + ln];

        f32x4 acc1[2][2];
        #pragma unroll
        for (int a = 0; a < 2; ++a)
            #pragma unroll
            for (int b = 0; b < 2; ++b)
                acc1[a][b] = (f32x4){0.f, 0.f, 0.f, 0.f};

        #pragma unroll
        for (int ks = 0; ks < 4; ++ks) {
            #pragma unroll
            for (int nt = 0; nt < 2; ++nt) {
                bf16x8 bfr = *(const bf16x8*)(w1buf + ((ks * 2 + nt) * 64 + lane) * 8);
                #pragma unroll
                for (int mt = 0; mt < 2; ++mt)
                    acc1[mt][nt] = __builtin_amdgcn_mfma_f32_16x16x32_bf16(
                        xf[mt * 4 + ks], bfr, acc1[mt][nt], 0, 0, 0);
            }
        }

        // bias+relu -> sH in A-frag order (this wave's rows only)
        #pragma unroll
        for (int nt = 0; nt < 2; ++nt) {
            float bias = bias_v[nt];
            int base = wave * 1024 + (nt * 2 + (ln >> 3)) * 128
                     + quad * 32 + (ln & 7);
            #pragma unroll
            for (int mt = 0; mt < 2; ++mt) {
                int fb = base + mt * 512;
                #pragma unroll
                for (int reg = 0; reg < 4; ++reg) {
                    float v = acc1[mt][nt][reg] + bias;
                    sH[fb + reg * 8] = (bf16)fmaxf(v, 0.f);
                }
            }
        }

        __syncthreads();   // B: all 128 sH rows visible; no DMAs outstanding

        // ---- prefetch chunk kc+1 (flies during stage 2, drained at next A) --
        {
            int nkc = (kc + 1) & 31;               // wrap: harmless refetch
            const bf16* w1src = W1g + (size_t)nkc * 4096;
            const bf16* w2src = W2g + (size_t)nkc * 8192;
            bf16* d1 = sW1[(kc + 1) & 1];
            bf16* d2 = sW2[(kc + 1) & 1];
            #pragma unroll
            for (int r = 0; r < 2; ++r) {
                int c = r * 4 + wave;
                cp16_async(w1src + c * 512 + lane * 8, d1 + c * 512);
            }
            #pragma unroll
            for (int r = 0; r < 4; ++r) {
                int c = r * 4 + wave;
                cp16_async(w2src + c * 512 + lane * 8, d2 + c * 512);
            }
        }

        // ---- stage 2: og[128 rows][this wave's 64 cols] += h @ W2c ----
        const bf16* w2buf = sW2[kc & 1];
        bf16x8 bb[4];
        #pragma unroll
        for (int nt = 0; nt < 4; ++nt)
            bb[nt] = *(const bf16x8*)(w2buf + ((wave * 4 + nt) * 64 + lane) * 8);
        #pragma unroll
        for (int mt = 0; mt < 8; ++mt) {
            bf16x8 a2 = *(const bf16x8*)(sH + (mt * 64 + lane) * 8);
            #pragma unroll
            for (int nt = 0; nt < 4; ++nt)
                acc2[mt][nt] = __builtin_amdgcn_mfma_f32_16x16x32_bf16(
                    a2, bb[nt], acc2[mt][nt], 0, 0, 0);
        }
    }

    // ---- epilogue: + b2, segment-max scatter via encoded atomicMax ----
    float b2v[4];
    #pragma unroll
    for (int nt = 0; nt < 4; ++nt) b2v[nt] = b2g[wave * 64 + nt * 16 + ln];

    #pragma unroll
    for (int mt = 0; mt < 8; ++mt)
        #pragma unroll
        for (int reg = 0; reg < 4; ++reg) {
            int row  = mt * 16 + quad * 4 + reg;
            int node = gI[row];
            uint32_t* dst = EMBu + (size_t)(node >> 4) * H_DIM
                          + n0t2 * 256 + wave * 64;
            #pragma unroll
            for (int nt = 0; nt < 4; ++nt) {
                float v = acc2[mt][nt][reg] + b2v[nt];
                atomicMax(dst + nt * 16 + ln, enc_f32(v));
            }
        }
}

// ---------------------------------------------------------------------------
// Per (coarse group, channel) mean / rsqrt(var+eps) over 256 fine rows.
// EMB holds order-encoded uint32; decode on read.
// ---------------------------------------------------------------------------
__global__ void stats_kernel(const uint32_t* __restrict__ EMBu,
                             float* __restrict__ MEAN,
                             float* __restrict__ RSIG)
{
    int gc = blockIdx.x;
    int ch = blockIdx.y * 128 + threadIdx.x;
    const uint32_t* p = EMBu + (size_t)gc * 256 * 512 + ch;
    float s = 0.f, ss = 0.f;
    #pragma unroll 4
    for (int r = 0; r < 256; ++r) {
        float v = dec_f32(p[(size_t)r * 512]);
        s += v; ss += v * v;
    }
    float mean = s * (1.f / 256.f);
    float var  = ss * (1.f / 256.f) - mean * mean;
    MEAN[gc * 512 + ch] = mean;
    RSIG[gc * 512 + ch] = rsqrtf(var + 1e-5f);
}

// ---------------------------------------------------------------------------
// logits[f][c] = b_out[c] + sum_h (emb[f][h]-mean)*rsig * w_out[h][c]
// ---------------------------------------------------------------------------
__global__ __launch_bounds__(256)
void classifier_kernel(const uint32_t* __restrict__ EMBu,
                       const float* __restrict__ MEAN,
                       const float* __restrict__ RSIG,
                       const float* __restrict__ w_out,
                       const float* __restrict__ b_out,
                       float* __restrict__ out)
{
    __shared__ float sW[512 * 16];
    __shared__ float sE[16 * 513];   // +1 pad breaks 4-way bank conflict
    int t  = threadIdx.x;
    int f0 = blockIdx.x * 16;
    int gc = f0 >> 8;

    #pragma unroll
    for (int it = 0; it < 8; ++it) {
        int i = (it * 256 + t) * 4;
        *(float4*)(sW + i) = *(const float4*)(w_out + i);
    }
    #pragma unroll
    for (int it = 0; it < 32; ++it) {
        int i  = it * 256 + t;
        int fr = i >> 9;
        int h  = i & 511;
        float v = dec_f32(EMBu[(size_t)(f0 + fr) * 512 + h]);
        sE[fr * 513 + h] = (v - MEAN[gc * 512 + h]) * RSIG[gc * 512 + h];
    }
    __syncthreads();

    int fr = t >> 4;
    int c  = t & 15;
    float acc = b_out[c];
    #pragma unroll 8
    for (int h = 0; h < 512; ++h)
        acc += sE[fr * 513 + h] * sW[h * 16 + c];
    out[(size_t)(f0 + fr) * 16 + c] = acc;
}

// ---------------------------------------------------------------------------
// Workspace layout (~21.1 MB): W1F 1 MB | W2F 4 MB | EMBu 16 MB | MEAN/RSIG
// ---------------------------------------------------------------------------
extern "C" void kernel_launch(void* const* d_in, const int* in_sizes, int n_in,
                              void* d_out, int out_size, void* d_ws, size_t ws_size,
                              hipStream_t stream)
{
    const float* x     = (const float*)d_in[0];
    const int*   gidx  = (const int*)d_in[1];
    const float* W1    = (const float*)d_in[4];
    const float* b1    = (const float*)d_in[5];
    const float* W2    = (const float*)d_in[6];
    const float* b2    = (const float*)d_in[7];
    const float* w_out = (const float*)d_in[8];
    const float* b_out = (const float*)d_in[9];
    float* out = (float*)d_out;

    char* w = (char*)d_ws;
    bf16* W1F = (bf16*)w;  w += (size_t)NGRP * KEXP * D_IN * 2;
    bf16* W2F = (bf16*)w;  w += (size_t)NGRP * H_DIM * KEXP * 2;
    uint32_t* EMBu = (uint32_t*)w; w += (size_t)F_SEG * H_DIM * 4;
    float* MEAN = (float*)w; w += (size_t)G_SEG * H_DIM * 4;
    float* RSIG = (float*)w; w += (size_t)G_SEG * H_DIM * 4;

    // 65536 (W1F) + 262144 (W2F) + 4194304 (EMB zero) threads
    convert_weights<<<17664, 256, 0, stream>>>(W1, W2, W1F, W2F, EMBu);
    mlp_kernel<<<2048, 256, 0, stream>>>(x, gidx, W1F, b1, W2F, b2, EMBu);
    stats_kernel<<<dim3(32, 4), 128, 0, stream>>>(EMBu, MEAN, RSIG);
    classifier_kernel<<<512, 256, 0, stream>>>(EMBu, MEAN, RSIG, w_out, b_out, out);
}

// Round 7
// 375.575 us; speedup vs baseline: 1.1884x; 1.1884x over previous
//
#include <hip/hip_runtime.h>
#include <stdint.h>

typedef __bf16 bf16;
typedef bf16 bf16x8 __attribute__((ext_vector_type(8)));
typedef float f32x4 __attribute__((ext_vector_type(4)));

#define N_NODES 131072
#define D_IN    128
#define KEXP    1024
#define H_DIM   512
#define NGRP    4
#define NPG     32768   // N_NODES / NGRP
#define F_SEG   8192
#define G_SEG   32
#define C_OUT   16

// async global->LDS DMA, 16B per lane; LDS dest = wave-uniform base + lane*16
typedef const __attribute__((address_space(1))) void* gas_t;
typedef __attribute__((address_space(3))) void* las_t;
__device__ __forceinline__ void cp16_async(const bf16* g, bf16* l) {
    __builtin_amdgcn_global_load_lds((gas_t)g, (las_t)l, 16, 0, 0);
}

// ---------------------------------------------------------------------------
// One-time weight cast + swizzle into MFMA-fragment order (16x16x32 bf16).
// B-frag: lane (quad=lane>>4, ln=lane&15) holds B[k=quad*8+j][n=ln].
// K-chunk = 32 (kc in [0,32)); N-tile = 256 (n0t2 in [0,2)).
//
// W1F[g][kc(32)][f=ks*2+nt (8)][lane(64)][j(8)]
//     = W1[g][d = ks*32 + quad*8 + j][k' = kc*32 + nt*16 + ln]
// W2F[g][n0t2(2)][kc(32)][f(16)][lane][j]
//     = W2[g][k = kc*32 + quad*8 + j][n = n0t2*256 + f*16 + ln]
// ---------------------------------------------------------------------------
__global__ void convert_weights(const float* __restrict__ W1,
                                const float* __restrict__ W2,
                                bf16* __restrict__ W1F,
                                bf16* __restrict__ W2F)
{
    int t = blockIdx.x * 256 + threadIdx.x;
    if (t < 65536) {
        int slot = t & 63, f = (t >> 6) & 7, kc = (t >> 9) & 31, g = t >> 14;
        int ks = f >> 1, nt = f & 1, quad = slot >> 4, ln = slot & 15;
        int k = kc * 32 + nt * 16 + ln;
        const float* src = W1 + ((size_t)(g * 128 + ks * 32 + quad * 8)) * 1024 + k;
        bf16x8 v;
        #pragma unroll
        for (int j = 0; j < 8; ++j) v[j] = (bf16)src[(size_t)j * 1024];
        *(bf16x8*)(W1F + (size_t)t * 8) = v;
    } else {
        int u = t - 65536;
        if (u < 262144) {
            int slot = u & 63, f = (u >> 6) & 15, kc = (u >> 10) & 31;
            int n0t2 = (u >> 15) & 1, g = u >> 16;
            int quad = slot >> 4, ln = slot & 15;
            int k = kc * 32 + quad * 8;
            int n = n0t2 * 256 + f * 16 + ln;
            const float* src = W2 + ((size_t)(g * 1024 + k)) * 512 + n;
            bf16x8 v;
            #pragma unroll
            for (int j = 0; j < 8; ++j) v[j] = (bf16)src[(size_t)j * 512];
            *(bf16x8*)(W2F + (size_t)u * 8) = v;
        }
    }
}

// ---------------------------------------------------------------------------
// Fused gather + GEMM1(relu) + GEMM2 + scatter. 256 threads (4 waves).
// Round-7: round-5 structure (NF store; R6's cross-XCD atomicMax epilogue
// doubled WRITE_SIZE and serialized at LLC -> reverted) + 2x2 wave-grid
// stage 2: wave (mg,ng) computes rows mg*64..+63 x cols ng*128..+127.
// Per-block-kc LDS reads: W1 32K + sH 16K (2x) + W2 32K (2x) = 80 KB
// (vs 104 KB in R5's wave-split-M; LDS pipe is the binding resource).
// Two barriers per kc, DMA prefetch SPLIT for max flight:
//   W2(kc+1) issued after barrier A -> drained at B (flies during stage 1)
//   W1(kc+1) issued after barrier B -> drained at next A (flies during stage 2)
// LDS: sW1 2x8K + sW2 2x16K + sH 8K = 56 KB -> 2 blocks/CU.
// ---------------------------------------------------------------------------
__global__ __launch_bounds__(256, 2)
void mlp_kernel(const float* __restrict__ x,
                const int*   __restrict__ gidx,
                const bf16*  __restrict__ W1F,
                const float* __restrict__ b1,
                const bf16*  __restrict__ W2F,
                const float* __restrict__ b2,
                bf16*        __restrict__ NF)
{
    __shared__ __align__(16) bf16 sW1[2][4096]; // [f=ks*2+nt (8)][lane][8]
    __shared__ __align__(16) bf16 sW2[2][8192]; // [f (16)][lane][8]
    __shared__ __align__(16) bf16 sH[4096];     // [frag m (8)][lane][8]

    const int tid  = threadIdx.x;
    const int bid  = blockIdx.x;
    const int g    = bid >> 9;
    const int rem  = bid & 511;
    const int m0   = (rem >> 1) * 128;
    const int n0t2 = rem & 1;

    const int wave = tid >> 6;
    const int lane = tid & 63;
    const int quad = lane >> 4;
    const int ln   = lane & 15;
    const int mg   = wave >> 1;   // stage-2 row group (64 rows)
    const int ng   = wave & 1;    // stage-2 col group (128 cols)

    const int*  gI  = gidx + g * NPG + m0;
    const bf16* W1g = W1F + (size_t)g * 131072;                   // [kc][4096]
    const bf16* W2g = W2F + (size_t)(g * 2 + n0t2) * 262144;      // [kc][8192]
    const float* b1g = b1 + g * KEXP;

    // ---- gather x A-frags straight into registers (reused all 32 kc) ----
    bf16x8 xf[8];
    #pragma unroll
    for (int i = 0; i < 8; ++i) {
        int row  = wave * 32 + (i >> 2) * 16 + ln;
        int node = gI[row];
        const float* src = x + (size_t)node * D_IN + (i & 3) * 32 + quad * 8;
        float4 a = *(const float4*)src;
        float4 b = *(const float4*)(src + 4);
        bf16x8 v;
        v[0] = (bf16)a.x; v[1] = (bf16)a.y; v[2] = (bf16)a.z; v[3] = (bf16)a.w;
        v[4] = (bf16)b.x; v[5] = (bf16)b.y; v[6] = (bf16)b.z; v[7] = (bf16)b.w;
        xf[i] = v;
    }

    f32x4 acc2[4][8];   // [mt: rows mg*64+mt*16][nt: cols ng*128+nt*16]
    #pragma unroll
    for (int a = 0; a < 4; ++a)
        #pragma unroll
        for (int b = 0; b < 8; ++b)
            acc2[a][b] = (f32x4){0.f, 0.f, 0.f, 0.f};

    // ---- preloop: DMA chunk 0 into buf 0 ----
    #pragma unroll
    for (int r = 0; r < 2; ++r) {
        int c = r * 4 + wave;
        cp16_async(W1g + c * 512 + lane * 8, sW1[0] + c * 512);
    }
    #pragma unroll
    for (int r = 0; r < 4; ++r) {
        int c = r * 4 + wave;
        cp16_async(W2g + c * 512 + lane * 8, sW2[0] + c * 512);
    }

    #pragma unroll 1
    for (int kc = 0; kc < 32; ++kc) {
        __syncthreads();   // A: drains W1(kc) DMA (flew during stage2(kc-1));
                           //    separates stage2(kc-1) sH reads from new writes

        // ---- prefetch W2(kc+1): drained at barrier B (stage-1 flight) ----
        {
            int nkc = (kc + 1) & 31;               // wrap: harmless refetch
            const bf16* w2src = W2g + (size_t)nkc * 8192;
            bf16* d2 = sW2[(kc + 1) & 1];
            #pragma unroll
            for (int r = 0; r < 4; ++r) {
                int c = r * 4 + wave;
                cp16_async(w2src + c * 512 + lane * 8, d2 + c * 512);
            }
        }

        // ---- stage 1: h[this wave's 32 rows][k' 32] = relu(x @ W1c + b1) ----
        const bf16* w1buf = sW1[kc & 1];
        float bias_v[2];
        #pragma unroll
        for (int nt = 0; nt < 2; ++nt)
            bias_v[nt] = b1g[kc * 32 + nt * 16 + ln];

        f32x4 acc1[2][2];
        #pragma unroll
        for (int a = 0; a < 2; ++a)
            #pragma unroll
            for (int b = 0; b < 2; ++b)
                acc1[a][b] = (f32x4){0.f, 0.f, 0.f, 0.f};

        #pragma unroll
        for (int ks = 0; ks < 4; ++ks) {
            #pragma unroll
            for (int nt = 0; nt < 2; ++nt) {
                bf16x8 bfr = *(const bf16x8*)(w1buf + ((ks * 2 + nt) * 64 + lane) * 8);
                #pragma unroll
                for (int mt = 0; mt < 2; ++mt)
                    acc1[mt][nt] = __builtin_amdgcn_mfma_f32_16x16x32_bf16(
                        xf[mt * 4 + ks], bfr, acc1[mt][nt], 0, 0, 0);
            }
        }

        // bias+relu -> sH in A-frag order (this wave's 2 frags)
        #pragma unroll
        for (int nt = 0; nt < 2; ++nt) {
            float bias = bias_v[nt];
            int base = wave * 1024 + (nt * 2 + (ln >> 3)) * 128
                     + quad * 32 + (ln & 7);
            #pragma unroll
            for (int mt = 0; mt < 2; ++mt) {
                int fb = base + mt * 512;
                #pragma unroll
                for (int reg = 0; reg < 4; ++reg) {
                    float v = acc1[mt][nt][reg] + bias;
                    sH[fb + reg * 8] = (bf16)fmaxf(v, 0.f);
                }
            }
        }

        __syncthreads();   // B: all 128 sH rows visible; drains W2(kc+1)

        // ---- prefetch W1(kc+1): drained at next A (stage-2 flight) ----
        {
            int nkc = (kc + 1) & 31;
            const bf16* w1src = W1g + (size_t)nkc * 4096;
            bf16* d1 = sW1[(kc + 1) & 1];
            #pragma unroll
            for (int r = 0; r < 2; ++r) {
                int c = r * 4 + wave;
                cp16_async(w1src + c * 512 + lane * 8, d1 + c * 512);
            }
        }

        // ---- stage 2: og[mg rows 64][ng cols 128] += h @ W2c ----
        const bf16* w2buf = sW2[kc & 1];
        bf16x8 bb[8];
        #pragma unroll
        for (int nt = 0; nt < 8; ++nt)
            bb[nt] = *(const bf16x8*)(w2buf + ((ng * 8 + nt) * 64 + lane) * 8);
        #pragma unroll
        for (int mt = 0; mt < 4; ++mt) {
            bf16x8 a2 = *(const bf16x8*)(sH + ((mg * 4 + mt) * 64 + lane) * 8);
            #pragma unroll
            for (int nt = 0; nt < 8; ++nt)
                acc2[mt][nt] = __builtin_amdgcn_mfma_f32_16x16x32_bf16(
                    a2, bb[nt], acc2[mt][nt], 0, 0, 0);
        }
    }

    // ---- epilogue: + b2, scatter rows to NF[node][H] as bf16 ----
    const float* b2g = b2 + g * H_DIM + n0t2 * 256 + ng * 128;
    float b2v[8];
    #pragma unroll
    for (int nt = 0; nt < 8; ++nt) b2v[nt] = b2g[nt * 16 + ln];

    #pragma unroll
    for (int mt = 0; mt < 4; ++mt)
        #pragma unroll
        for (int reg = 0; reg < 4; ++reg) {
            int row  = mg * 64 + mt * 16 + quad * 4 + reg;
            int node = gI[row];
            bf16* dst = NF + (size_t)node * H_DIM + n0t2 * 256 + ng * 128;
            #pragma unroll
            for (int nt = 0; nt < 8; ++nt)
                dst[nt * 16 + ln] = (bf16)(acc2[mt][nt][reg] + b2v[nt]);
        }
}

// ---------------------------------------------------------------------------
// segment_max over 16 consecutive nodes per fine cluster (sorted arange ids).
// Thread handles one (f, 8-channel group); uint4 loads (16 B/lane).
// ---------------------------------------------------------------------------
__global__ void pool_kernel(const bf16* __restrict__ NF, float* __restrict__ EMB)
{
    int t  = blockIdx.x * 256 + threadIdx.x;    // 524288 total
    int f  = t >> 6;
    int c8 = (t & 63) * 8;
    const uint4* src = (const uint4*)(NF + (size_t)f * 16 * 512 + c8);
    float m[8];
    #pragma unroll
    for (int i = 0; i < 8; ++i) m[i] = -INFINITY;
    #pragma unroll
    for (int r = 0; r < 16; ++r) {
        uint4 v = src[(size_t)r * 64];
        uint32_t w[4] = {v.x, v.y, v.z, v.w};
        #pragma unroll
        for (int i = 0; i < 4; ++i) {
            m[2*i]   = fmaxf(m[2*i],   __uint_as_float(w[i] << 16));
            m[2*i+1] = fmaxf(m[2*i+1], __uint_as_float(w[i] & 0xffff0000u));
        }
    }
    float* dst = EMB + (size_t)f * 512 + c8;
    *(float4*)dst       = make_float4(m[0], m[1], m[2], m[3]);
    *(float4*)(dst + 4) = make_float4(m[4], m[5], m[6], m[7]);
}

// ---------------------------------------------------------------------------
// Per (coarse group, channel) mean / rsqrt(var+eps) over 256 fine rows.
// ---------------------------------------------------------------------------
__global__ void stats_kernel(const float* __restrict__ EMB,
                             float* __restrict__ MEAN,
                             float* __restrict__ RSIG)
{
    int gc = blockIdx.x;
    int ch = blockIdx.y * 128 + threadIdx.x;
    const float* p = EMB + (size_t)gc * 256 * 512 + ch;
    float s = 0.f, ss = 0.f;
    #pragma unroll 4
    for (int r = 0; r < 256; ++r) {
        float v = p[(size_t)r * 512];
        s += v; ss += v * v;
    }
    float mean = s * (1.f / 256.f);
    float var  = ss * (1.f / 256.f) - mean * mean;
    MEAN[gc * 512 + ch] = mean;
    RSIG[gc * 512 + ch] = rsqrtf(var + 1e-5f);
}

// ---------------------------------------------------------------------------
// logits[f][c] = b_out[c] + sum_h (emb[f][h]-mean)*rsig * w_out[h][c]
// ---------------------------------------------------------------------------
__global__ __launch_bounds__(256)
void classifier_kernel(const float* __restrict__ EMB,
                       const float* __restrict__ MEAN,
                       const float* __restrict__ RSIG,
                       const float* __restrict__ w_out,
                       const float* __restrict__ b_out,
                       float* __restrict__ out)
{
    __shared__ float sW[512 * 16];
    __shared__ float sE[16 * 513];   // +1 pad breaks 4-way bank conflict
    int t  = threadIdx.x;
    int f0 = blockIdx.x * 16;
    int gc = f0 >> 8;

    #pragma unroll
    for (int it = 0; it < 8; ++it) {
        int i = (it * 256 + t) * 4;
        *(float4*)(sW + i) = *(const float4*)(w_out + i);
    }
    #pragma unroll
    for (int it = 0; it < 32; ++it) {
        int i  = it * 256 + t;
        int fr = i >> 9;
        int h  = i & 511;
        float v = EMB[(size_t)(f0 + fr) * 512 + h];
        sE[fr * 513 + h] = (v - MEAN[gc * 512 + h]) * RSIG[gc * 512 + h];
    }
    __syncthreads();

    int fr = t >> 4;
    int c  = t & 15;
    float acc = b_out[c];
    #pragma unroll 8
    for (int h = 0; h < 512; ++h)
        acc += sE[fr * 513 + h] * sW[h * 16 + c];
    out[(size_t)(f0 + fr) * 16 + c] = acc;
}

// ---------------------------------------------------------------------------
// Workspace layout (~156.4 MB):
//   W1F 1 MB | W2F 4 MB | NF 134 MB | EMB 16 MB | MEAN 64K | RSIG 64K
// ---------------------------------------------------------------------------
extern "C" void kernel_launch(void* const* d_in, const int* in_sizes, int n_in,
                              void* d_out, int out_size, void* d_ws, size_t ws_size,
                              hipStream_t stream)
{
    const float* x     = (const float*)d_in[0];
    const int*   gidx  = (const int*)d_in[1];
    const float* W1    = (const float*)d_in[4];
    const float* b1    = (const float*)d_in[5];
    const float* W2    = (const float*)d_in[6];
    const float* b2    = (const float*)d_in[7];
    const float* w_out = (const float*)d_in[8];
    const float* b_out = (const float*)d_in[9];
    float* out = (float*)d_out;

    char* w = (char*)d_ws;
    bf16* W1F = (bf16*)w;  w += (size_t)NGRP * KEXP * D_IN * 2;
    bf16* W2F = (bf16*)w;  w += (size_t)NGRP * H_DIM * KEXP * 2;
    bf16* NF  = (bf16*)w;  w += (size_t)N_NODES * H_DIM * 2;
    float* EMB  = (float*)w; w += (size_t)F_SEG * H_DIM * 4;
    float* MEAN = (float*)w; w += (size_t)G_SEG * H_DIM * 4;
    float* RSIG = (float*)w; w += (size_t)G_SEG * H_DIM * 4;

    convert_weights<<<1280, 256, 0, stream>>>(W1, W2, W1F, W2F);
    mlp_kernel<<<2048, 256, 0, stream>>>(x, gidx, W1F, b1, W2F, b2, NF);
    pool_kernel<<<2048, 256, 0, stream>>>(NF, EMB);
    stats_kernel<<<dim3(32, 4), 128, 0, stream>>>(EMB, MEAN, RSIG);
    classifier_kernel<<<512, 256, 0, stream>>>(EMB, MEAN, RSIG, w_out, b_out, out);
}

// Round 8
// 367.799 us; speedup vs baseline: 1.2135x; 1.0211x over previous
//
#include <hip/hip_runtime.h>
#include <stdint.h>

typedef __bf16 bf16;
typedef bf16 bf16x4 __attribute__((ext_vector_type(4)));
typedef bf16 bf16x8 __attribute__((ext_vector_type(8)));
typedef float f32x4 __attribute__((ext_vector_type(4)));

#define N_NODES 131072
#define D_IN    128
#define KEXP    1024
#define H_DIM   512
#define NGRP    4
#define NPG     32768   // N_NODES / NGRP
#define F_SEG   8192
#define G_SEG   32
#define C_OUT   16

// async global->LDS DMA, 16B per lane; LDS dest = wave-uniform base + lane*16
typedef const __attribute__((address_space(1))) void* gas_t;
typedef __attribute__((address_space(3))) void* las_t;
__device__ __forceinline__ void cp16_async(const bf16* g, bf16* l) {
    __builtin_amdgcn_global_load_lds((gas_t)g, (las_t)l, 16, 0, 0);
}

// ---------------------------------------------------------------------------
// One-time weight cast + swizzle into MFMA-fragment order (16x16x32 bf16).
// B-frag: lane (quad=lane>>4, ln=lane&15) holds B[k=quad*8+j][n=ln].
// (The same physical layout serves as A-frag with rows=ln, k=quad*8+j.)
//
// W1F[g][kc(32)][f=ks*2+kt (8)][lane(64)][j(8)]
//     = W1[g][d = ks*32 + quad*8 + j][k' = kc*32 + kt*16 + ln]
// W2F[g][n0t2(2)][kc(32)][f(16)][lane][j]
//     = W2[g][k = kc*32 + quad*8 + j][n = n0t2*256 + f*16 + ln]
// ---------------------------------------------------------------------------
__global__ void convert_weights(const float* __restrict__ W1,
                                const float* __restrict__ W2,
                                bf16* __restrict__ W1F,
                                bf16* __restrict__ W2F)
{
    int t = blockIdx.x * 256 + threadIdx.x;
    if (t < 65536) {
        int slot = t & 63, f = (t >> 6) & 7, kc = (t >> 9) & 31, g = t >> 14;
        int ks = f >> 1, kt = f & 1, quad = slot >> 4, ln = slot & 15;
        int k = kc * 32 + kt * 16 + ln;
        const float* src = W1 + ((size_t)(g * 128 + ks * 32 + quad * 8)) * 1024 + k;
        bf16x8 v;
        #pragma unroll
        for (int j = 0; j < 8; ++j) v[j] = (bf16)src[(size_t)j * 1024];
        *(bf16x8*)(W1F + (size_t)t * 8) = v;
    } else {
        int u = t - 65536;
        if (u < 262144) {
            int slot = u & 63, f = (u >> 6) & 15, kc = (u >> 10) & 31;
            int n0t2 = (u >> 15) & 1, g = u >> 16;
            int quad = slot >> 4, ln = slot & 15;
            int k = kc * 32 + quad * 8;
            int n = n0t2 * 256 + f * 16 + ln;
            const float* src = W2 + ((size_t)(g * 1024 + k)) * 512 + n;
            bf16x8 v;
            #pragma unroll
            for (int j = 0; j < 8; ++j) v[j] = (bf16)src[(size_t)j * 512];
            *(bf16x8*)(W2F + (size_t)u * 8) = v;
        }
    }
}

// ---------------------------------------------------------------------------
// Fused gather + GEMM1(relu) + GEMM2 + scatter. 256 threads (4 waves).
// Round-8: operand-SWAPPED stage 1 — D = (W1 as A)·(x as B) = h^T[k'][m],
// so each lane's 4 acc regs are 4 CONSECUTIVE k' at fixed m: sH store is
// 4x ds_write_b64 (2-way = free) instead of 32 conflicted ds_write_b16.
// (R7 books: sH writes+conflicts ~640 of 1890 LDS cyc/block-kc.)
// W1F/xf need no layout change: the B-frag layout doubles as A-frag.
// Stage 2: 2x2 wave grid, wave (mg,ng) = rows mg*64..+63 x cols ng*128..+127.
// Two barriers per kc, DMA prefetch split for max flight:
//   W2(kc+1) after barrier A (drained at B);  W1(kc+1) after B (drained at A).
// LDS: sW1 2x8K + sW2 2x16K + sH 8K = 56 KB -> 2 blocks/CU.
// ---------------------------------------------------------------------------
__global__ __launch_bounds__(256, 2)
void mlp_kernel(const float* __restrict__ x,
                const int*   __restrict__ gidx,
                const bf16*  __restrict__ W1F,
                const float* __restrict__ b1,
                const bf16*  __restrict__ W2F,
                const float* __restrict__ b2,
                bf16*        __restrict__ NF)
{
    __shared__ __align__(16) bf16 sW1[2][4096]; // [f=ks*2+kt (8)][lane][8]
    __shared__ __align__(16) bf16 sW2[2][8192]; // [f (16)][lane][8]
    __shared__ __align__(16) bf16 sH[4096];     // A-frag order [fm (8)][lane][8]

    const int tid  = threadIdx.x;
    const int bid  = blockIdx.x;
    const int g    = bid >> 9;
    const int rem  = bid & 511;
    const int m0   = (rem >> 1) * 128;
    const int n0t2 = rem & 1;

    const int wave = tid >> 6;
    const int lane = tid & 63;
    const int quad = lane >> 4;
    const int ln   = lane & 15;
    const int mg   = wave >> 1;   // stage-2 row group (64 rows)
    const int ng   = wave & 1;    // stage-2 col group (128 cols)

    const int*  gI  = gidx + g * NPG + m0;
    const bf16* W1g = W1F + (size_t)g * 131072;                   // [kc][4096]
    const bf16* W2g = W2F + (size_t)(g * 2 + n0t2) * 262144;      // [kc][8192]
    const float* b1g = b1 + g * KEXP;

    // ---- gather x B-frags straight into registers (reused all 32 kc) ----
    // frag i (mt=i>>2, ks=i&3): lane holds x[row=wave*32+mt*16+ln][ks*32+quad*8 ..+8)
    bf16x8 xf[8];
    #pragma unroll
    for (int i = 0; i < 8; ++i) {
        int row  = wave * 32 + (i >> 2) * 16 + ln;
        int node = gI[row];
        const float* src = x + (size_t)node * D_IN + (i & 3) * 32 + quad * 8;
        float4 a = *(const float4*)src;
        float4 b = *(const float4*)(src + 4);
        bf16x8 v;
        v[0] = (bf16)a.x; v[1] = (bf16)a.y; v[2] = (bf16)a.z; v[3] = (bf16)a.w;
        v[4] = (bf16)b.x; v[5] = (bf16)b.y; v[6] = (bf16)b.z; v[7] = (bf16)b.w;
        xf[i] = v;
    }

    f32x4 acc2[4][8];   // [mt: rows mg*64+mt*16][nt: cols ng*128+nt*16]
    #pragma unroll
    for (int a = 0; a < 4; ++a)
        #pragma unroll
        for (int b = 0; b < 8; ++b)
            acc2[a][b] = (f32x4){0.f, 0.f, 0.f, 0.f};

    // ---- preloop: DMA chunk 0 into buf 0 ----
    #pragma unroll
    for (int r = 0; r < 2; ++r) {
        int c = r * 4 + wave;
        cp16_async(W1g + c * 512 + lane * 8, sW1[0] + c * 512);
    }
    #pragma unroll
    for (int r = 0; r < 4; ++r) {
        int c = r * 4 + wave;
        cp16_async(W2g + c * 512 + lane * 8, sW2[0] + c * 512);
    }

    #pragma unroll 1
    for (int kc = 0; kc < 32; ++kc) {
        __syncthreads();   // A: drains W1(kc) DMA (flew during stage2(kc-1));
                           //    separates stage2(kc-1) sH reads from new writes

        // ---- prefetch W2(kc+1): drained at barrier B (stage-1 flight) ----
        {
            int nkc = (kc + 1) & 31;               // wrap: harmless refetch
            const bf16* w2src = W2g + (size_t)nkc * 8192;
            bf16* d2 = sW2[(kc + 1) & 1];
            #pragma unroll
            for (int r = 0; r < 4; ++r) {
                int c = r * 4 + wave;
                cp16_async(w2src + c * 512 + lane * 8, d2 + c * 512);
            }
        }

        // ---- stage 1 (swapped): D[k'][m] = W1c^T-tile x x-tile ----
        // acc1[kt][mt]: rows k' = kt*16+quad*4+reg, cols m = mt*16+ln
        const bf16* w1buf = sW1[kc & 1];
        f32x4 acc1[2][2];
        #pragma unroll
        for (int a = 0; a < 2; ++a)
            #pragma unroll
            for (int b = 0; b < 2; ++b)
                acc1[a][b] = (f32x4){0.f, 0.f, 0.f, 0.f};

        #pragma unroll
        for (int ks = 0; ks < 4; ++ks) {
            #pragma unroll
            for (int kt = 0; kt < 2; ++kt) {
                bf16x8 w1f = *(const bf16x8*)(w1buf + ((ks * 2 + kt) * 64 + lane) * 8);
                #pragma unroll
                for (int mt = 0; mt < 2; ++mt)
                    acc1[kt][mt] = __builtin_amdgcn_mfma_f32_16x16x32_bf16(
                        w1f, xf[mt * 4 + ks], acc1[kt][mt], 0, 0, 0);
            }
        }

        // bias+relu -> sH via b64 stores (4 contiguous k' per lane at fixed m)
        // value: h[m = wave*32+mt*16+ln][k' = kt*16+quad*4+reg]
        // dest A-frag elem: fm = wave*2+mt, qa = kt*2+(quad>>1), j = (quad&1)*4+reg
        #pragma unroll
        for (int kt = 0; kt < 2; ++kt) {
            float4 bv = *(const float4*)(b1g + kc * 32 + kt * 16 + quad * 4);
            float bvr[4] = {bv.x, bv.y, bv.z, bv.w};
            int qa = kt * 2 + (quad >> 1);
            int j0 = (quad & 1) * 4;
            #pragma unroll
            for (int mt = 0; mt < 2; ++mt) {
                int fm = wave * 2 + mt;
                bf16x4 pk;
                #pragma unroll
                for (int reg = 0; reg < 4; ++reg)
                    pk[reg] = (bf16)fmaxf(acc1[kt][mt][reg] + bvr[reg], 0.f);
                *(bf16x4*)(sH + (fm * 64 + qa * 16 + ln) * 8 + j0) = pk;
            }
        }

        __syncthreads();   // B: all 128 sH rows visible; drains W2(kc+1)

        // ---- prefetch W1(kc+1): drained at next A (stage-2 flight) ----
        {
            int nkc = (kc + 1) & 31;
            const bf16* w1src = W1g + (size_t)nkc * 4096;
            bf16* d1 = sW1[(kc + 1) & 1];
            #pragma unroll
            for (int r = 0; r < 2; ++r) {
                int c = r * 4 + wave;
                cp16_async(w1src + c * 512 + lane * 8, d1 + c * 512);
            }
        }

        // ---- stage 2: og[mg rows 64][ng cols 128] += h @ W2c ----
        const bf16* w2buf = sW2[kc & 1];
        bf16x8 bb[8];
        #pragma unroll
        for (int nt = 0; nt < 8; ++nt)
            bb[nt] = *(const bf16x8*)(w2buf + ((ng * 8 + nt) * 64 + lane) * 8);
        #pragma unroll
        for (int mt = 0; mt < 4; ++mt) {
            bf16x8 a2 = *(const bf16x8*)(sH + ((mg * 4 + mt) * 64 + lane) * 8);
            #pragma unroll
            for (int nt = 0; nt < 8; ++nt)
                acc2[mt][nt] = __builtin_amdgcn_mfma_f32_16x16x32_bf16(
                    a2, bb[nt], acc2[mt][nt], 0, 0, 0);
        }
    }

    // ---- epilogue: + b2, scatter rows to NF[node][H] as bf16 ----
    const float* b2g = b2 + g * H_DIM + n0t2 * 256 + ng * 128;
    float b2v[8];
    #pragma unroll
    for (int nt = 0; nt < 8; ++nt) b2v[nt] = b2g[nt * 16 + ln];

    #pragma unroll
    for (int mt = 0; mt < 4; ++mt)
        #pragma unroll
        for (int reg = 0; reg < 4; ++reg) {
            int row  = mg * 64 + mt * 16 + quad * 4 + reg;
            int node = gI[row];
            bf16* dst = NF + (size_t)node * H_DIM + n0t2 * 256 + ng * 128;
            #pragma unroll
            for (int nt = 0; nt < 8; ++nt)
                dst[nt * 16 + ln] = (bf16)(acc2[mt][nt][reg] + b2v[nt]);
        }
}

// ---------------------------------------------------------------------------
// segment_max over 16 consecutive nodes per fine cluster (sorted arange ids).
// Thread handles one (f, 8-channel group); uint4 loads (16 B/lane).
// ---------------------------------------------------------------------------
__global__ void pool_kernel(const bf16* __restrict__ NF, float* __restrict__ EMB)
{
    int t  = blockIdx.x * 256 + threadIdx.x;    // 524288 total
    int f  = t >> 6;
    int c8 = (t & 63) * 8;
    const uint4* src = (const uint4*)(NF + (size_t)f * 16 * 512 + c8);
    float m[8];
    #pragma unroll
    for (int i = 0; i < 8; ++i) m[i] = -INFINITY;
    #pragma unroll
    for (int r = 0; r < 16; ++r) {
        uint4 v = src[(size_t)r * 64];
        uint32_t w[4] = {v.x, v.y, v.z, v.w};
        #pragma unroll
        for (int i = 0; i < 4; ++i) {
            m[2*i]   = fmaxf(m[2*i],   __uint_as_float(w[i] << 16));
            m[2*i+1] = fmaxf(m[2*i+1], __uint_as_float(w[i] & 0xffff0000u));
        }
    }
    float* dst = EMB + (size_t)f * 512 + c8;
    *(float4*)dst       = make_float4(m[0], m[1], m[2], m[3]);
    *(float4*)(dst + 4) = make_float4(m[4], m[5], m[6], m[7]);
}

// ---------------------------------------------------------------------------
// Per (coarse group, channel) mean / rsqrt(var+eps) over 256 fine rows.
// ---------------------------------------------------------------------------
__global__ void stats_kernel(const float* __restrict__ EMB,
                             float* __restrict__ MEAN,
                             float* __restrict__ RSIG)
{
    int gc = blockIdx.x;
    int ch = blockIdx.y * 128 + threadIdx.x;
    const float* p = EMB + (size_t)gc * 256 * 512 + ch;
    float s = 0.f, ss = 0.f;
    #pragma unroll 4
    for (int r = 0; r < 256; ++r) {
        float v = p[(size_t)r * 512];
        s += v; ss += v * v;
    }
    float mean = s * (1.f / 256.f);
    float var  = ss * (1.f / 256.f) - mean * mean;
    MEAN[gc * 512 + ch] = mean;
    RSIG[gc * 512 + ch] = rsqrtf(var + 1e-5f);
}

// ---------------------------------------------------------------------------
// logits[f][c] = b_out[c] + sum_h (emb[f][h]-mean)*rsig * w_out[h][c]
// ---------------------------------------------------------------------------
__global__ __launch_bounds__(256)
void classifier_kernel(const float* __restrict__ EMB,
                       const float* __restrict__ MEAN,
                       const float* __restrict__ RSIG,
                       const float* __restrict__ w_out,
                       const float* __restrict__ b_out,
                       float* __restrict__ out)
{
    __shared__ float sW[512 * 16];
    __shared__ float sE[16 * 513];   // +1 pad breaks 4-way bank conflict
    int t  = threadIdx.x;
    int f0 = blockIdx.x * 16;
    int gc = f0 >> 8;

    #pragma unroll
    for (int it = 0; it < 8; ++it) {
        int i = (it * 256 + t) * 4;
        *(float4*)(sW + i) = *(const float4*)(w_out + i);
    }
    #pragma unroll
    for (int it = 0; it < 32; ++it) {
        int i  = it * 256 + t;
        int fr = i >> 9;
        int h  = i & 511;
        float v = EMB[(size_t)(f0 + fr) * 512 + h];
        sE[fr * 513 + h] = (v - MEAN[gc * 512 + h]) * RSIG[gc * 512 + h];
    }
    __syncthreads();

    int fr = t >> 4;
    int c  = t & 15;
    float acc = b_out[c];
    #pragma unroll 8
    for (int h = 0; h < 512; ++h)
        acc += sE[fr * 513 + h] * sW[h * 16 + c];
    out[(size_t)(f0 + fr) * 16 + c] = acc;
}

// ---------------------------------------------------------------------------
// Workspace layout (~156.4 MB):
//   W1F 1 MB | W2F 4 MB | NF 134 MB | EMB 16 MB | MEAN 64K | RSIG 64K
// ---------------------------------------------------------------------------
extern "C" void kernel_launch(void* const* d_in, const int* in_sizes, int n_in,
                              void* d_out, int out_size, void* d_ws, size_t ws_size,
                              hipStream_t stream)
{
    const float* x     = (const float*)d_in[0];
    const int*   gidx  = (const int*)d_in[1];
    const float* W1    = (const float*)d_in[4];
    const float* b1    = (const float*)d_in[5];
    const float* W2    = (const float*)d_in[6];
    const float* b2    = (const float*)d_in[7];
    const float* w_out = (const float*)d_in[8];
    const float* b_out = (const float*)d_in[9];
    float* out = (float*)d_out;

    char* w = (char*)d_ws;
    bf16* W1F = (bf16*)w;  w += (size_t)NGRP * KEXP * D_IN * 2;
    bf16* W2F = (bf16*)w;  w += (size_t)NGRP * H_DIM * KEXP * 2;
    bf16* NF  = (bf16*)w;  w += (size_t)N_NODES * H_DIM * 2;
    float* EMB  = (float*)w; w += (size_t)F_SEG * H_DIM * 4;
    float* MEAN = (float*)w; w += (size_t)G_SEG * H_DIM * 4;
    float* RSIG = (float*)w; w += (size_t)G_SEG * H_DIM * 4;

    convert_weights<<<1280, 256, 0, stream>>>(W1, W2, W1F, W2F);
    mlp_kernel<<<2048, 256, 0, stream>>>(x, gidx, W1F, b1, W2F, b2, NF);
    pool_kernel<<<2048, 256, 0, stream>>>(NF, EMB);
    stats_kernel<<<dim3(32, 4), 128, 0, stream>>>(EMB, MEAN, RSIG);
    classifier_kernel<<<512, 256, 0, stream>>>(EMB, MEAN, RSIG, w_out, b_out, out);
}